// Round 5
// baseline (489.543 us; speedup 1.0000x reference)
//
#include <hip/hip_runtime.h>

#define HH 512
#define WW 512
#define NB 4
#define NC 25              // final channel count: 1 + 12*2
#define HWs (HH * WW)

__device__ __forceinline__ int refl(int p, int n) {
    // jnp.pad mode='reflect' (no edge repeat); single reflection valid for |pad| < n
    p = (p < 0) ? -p : p;
    p = (p >= n) ? (2 * n - 2 - p) : p;
    return p;
}

__global__ __launch_bounds__(256) void copy_x_kernel(const float* __restrict__ x,
                                                     float* __restrict__ out) {
    int t = blockIdx.x * 256 + threadIdx.x;   // NB*HWs/4 = 262144 threads
    int b = t >> 16;                          // HWs/4 = 65536 float4 per batch
    int r = t & 65535;
    const float4* src = (const float4*)(x + (size_t)b * HWs);
    float4* dst = (float4*)(out + (size_t)b * NC * HWs);
    dst[r] = src[r];
}

// Wave-private pipeline, NO __syncthreads anywhere.
// Block = 4 waves; wave = 1 output row x 256 cols (lane owns cols lane+64k).
// Each wave double-buffers its own 3 input rows in a private LDS region via
// global_load_lds (16B/lane, dst 16B-aligned thanks to DILP padding); halo
// (reflected cols) via scalar loads issued BEFORE the main lds-loads.
// Per-wave stalls (vmcnt) are hidden by 16 waves/CU TLP instead of being
// block-wide barrier drains (the R4 failure mode).
template <int NIN, int DIL>
__global__ __launch_bounds__(256) void msd_layer(const float* __restrict__ wts,
                                                 const float* __restrict__ bias,
                                                 float* __restrict__ buf,
                                                 int layer) {
    constexpr int DILP = (DIL + 3) / 4 * 4;   // left-halo pad for 16B LDS alignment
    constexpr int SEG = 256 + 2 * DILP;       // staged floats per row
    constexpr int WSTR = 3 * SEG;             // floats per (wave, buf)
    constexpr int NHALO = 6 * DIL;            // halo elems per wave-channel
    constexpr int HI = (NHALO + 63) / 64;     // halo iters per lane (1 or 2)

    __shared__ __align__(16) float lds[4][2][WSTR];

    const int tid = threadIdx.x;
    const int li = tid & 63;
    const int wv = __builtin_amdgcn_readfirstlane(tid >> 6);
    const int blk = blockIdx.x;
    const int b = blk >> 8;                   // 256 blocks per image
    const int rem = blk & 255;
    const int rg = rem >> 1;                  // row group 0..127
    const int w0 = (rem & 1) << 8;            // column half base
    const int row = rg * 4 + wv;              // this wave's output row (uniform)

    const float* base = buf + (size_t)b * NC * HWs;

    // 3 input-row element offsets (wave-uniform)
    int grow[3];
#pragma unroll
    for (int r = 0; r < 3; ++r) grow[r] = refl(row + (r - 1) * DIL, HH) * WW;

    // Halo descriptors (channel-invariant): staged col s maps to img col
    // w0 - DILP + s for s in [DILP-DIL, DILP) (left) and [DILP+256, DILP+256+DIL) (right)
    int hsrc[HI], hdst[HI];
    bool hv[HI];
#pragma unroll
    for (int it = 0; it < HI; ++it) {
        int u = li + it * 64;
        hv[it] = (u < NHALO);
        int uu = hv[it] ? u : 0;
        int r = uu / (2 * DIL);
        int t = uu - r * 2 * DIL;
        int side = (t >= DIL);                // 0 = left halo, 1 = right halo
        int j = side ? t - DIL : t;
        int col = refl(w0 + (side ? 256 + j : j - DIL), WW);
        hsrc[it] = grow[r] + col;
        hdst[it] = r * SEG + (side ? DILP + 256 + j : DILP - DIL + j);
    }

    auto stage = [&](int c, int pb) {
        const float* plane = base + (size_t)c * HWs;
        float* L = &lds[wv][pb][0];
        // halo loads first so their ds_write wait doesn't drain the main lds-loads
        float hval[HI];
#pragma unroll
        for (int it = 0; it < HI; ++it) hval[it] = hv[it] ? plane[hsrc[it]] : 0.f;
#pragma unroll
        for (int r = 0; r < 3; ++r)
            __builtin_amdgcn_global_load_lds(
                (const __attribute__((address_space(1))) void*)(plane + grow[r] + w0 + li * 4),
                (__attribute__((address_space(3))) void*)(L + r * SEG + DILP + li * 4), 16, 0, 0);
#pragma unroll
        for (int it = 0; it < HI; ++it)
            if (hv[it]) L[hdst[it]] = hval[it];
    };

    stage(0, 0);

    const float b0 = bias[2 * layer];
    const float b1 = bias[2 * layer + 1];
    float a0[4] = {b0, b0, b0, b0};
    float a1[4] = {b1, b1, b1, b1};

    for (int c = 0; c < NIN; ++c) {
        if (c + 1 < NIN) stage(c + 1, (c + 1) & 1);

        float wk0[9], wk1[9];
#pragma unroll
        for (int k = 0; k < 9; ++k) {
            wk0[k] = wts[c * 9 + k];             // out-ch 0
            wk1[k] = wts[(NIN + c) * 9 + k];     // out-ch 1
        }

        const float* L = &lds[wv][c & 1][0];
#pragma unroll
        for (int g = 0; g < 3; ++g) {
            const float* Lg = L + g * SEG + DILP + li;
#pragma unroll
            for (int kw = 0; kw < 3; ++kw) {
                const float* q = Lg + (kw - 1) * DIL;
                const float wa = wk0[g * 3 + kw];
                const float wb = wk1[g * 3 + kw];
#pragma unroll
                for (int k = 0; k < 4; ++k) {
                    float v = q[64 * k];         // stride-1 across lanes: conflict-free
                    a0[k] = fmaf(v, wa, a0[k]);
                    a1[k] = fmaf(v, wb, a1[k]);
                }
            }
        }
    }

    float* o0 = buf + (size_t)(b * NC + NIN) * HWs + (size_t)row * WW + w0 + li;
    float* o1 = o0 + HWs;
#pragma unroll
    for (int k = 0; k < 4; ++k) {
        o0[64 * k] = fmaxf(a0[k], 0.f);
        o1[64 * k] = fmaxf(a1[k], 0.f);
    }
}

extern "C" void kernel_launch(void* const* d_in, const int* in_sizes, int n_in,
                              void* d_out, int out_size, void* d_ws, size_t ws_size,
                              hipStream_t stream) {
    const float* x = (const float*)d_in[0];
    const float* bias = (const float*)d_in[1];
    float* out = (float*)d_out;

    copy_x_kernel<<<1024, 256, 0, stream>>>(x, out);

    const int blocks = NB * 256;  // 1024: 4 img x 128 row-groups x 2 col-halves

#define LAYER(i, nin, dil) \
    msd_layer<nin, dil><<<blocks, 256, 0, stream>>>((const float*)d_in[2 + i], bias, out, i)

    LAYER(0, 1, 1);
    LAYER(1, 3, 2);
    LAYER(2, 5, 3);
    LAYER(3, 7, 4);
    LAYER(4, 9, 5);
    LAYER(5, 11, 6);
    LAYER(6, 13, 7);
    LAYER(7, 15, 8);
    LAYER(8, 17, 9);
    LAYER(9, 19, 10);
    LAYER(10, 21, 11);
    LAYER(11, 23, 12);
#undef LAYER
}